// Round 1
// baseline (1144.486 us; speedup 1.0000x reference)
//
#include <hip/hip_runtime.h>
#include <cstdint>

#define TK 2048     // tokens
#define DM 1024     // d_model
#define NE 8        // experts
#define NF 2048     // expert hidden
#define NV 32000    // vocab
#define CAP 640     // int(1.25 * 2 * 2048 / 8)

typedef short bf16x8 __attribute__((ext_vector_type(8)));
typedef float floatx4 __attribute__((ext_vector_type(4)));

__device__ __forceinline__ unsigned short f2bf(float x){
  unsigned u = __float_as_uint(x);
  u += 0x7FFFu + ((u >> 16) & 1u);
  return (unsigned short)(u >> 16);
}
__device__ __forceinline__ float bf2f(unsigned short h){
  return __uint_as_float(((unsigned)h) << 16);
}
__device__ __forceinline__ float gelu_tanh(float x){
  float x3 = x*x*x;
  return 0.5f*x*(1.0f + tanhf(0.7978845608028654f*(x + 0.044715f*x3)));
}

// ---------- fp32 -> bf16 convert (vectorized) ----------
__global__ void k_convert_bf16(const float* __restrict__ in, unsigned short* __restrict__ out, long n4){
  long i = (long)blockIdx.x*blockDim.x + threadIdx.x;
  if (i >= n4) return;
  float4 v = ((const float4*)in)[i];
  ushort4 o;
  o.x = f2bf(v.x); o.y = f2bf(v.y); o.z = f2bf(v.z); o.w = f2bf(v.w);
  ((ushort4*)out)[i] = o;
}

// ---------- batched transpose fp32 [B,R,C] -> bf16 hi/lo [B,C,R] ----------
__global__ void k_transpose_split(const float* __restrict__ in, unsigned short* __restrict__ hi,
                                  unsigned short* __restrict__ lo, int R, int C){
  __shared__ float tile[32][33];
  const int b = blockIdx.z;
  const float* src = in + (long)b*R*C;
  const int c0 = blockIdx.x*32, r0 = blockIdx.y*32;
  const int tx = threadIdx.x, ty = threadIdx.y;
#pragma unroll
  for (int j=0;j<4;j++){
    int rr = ty + j*8;
    tile[rr][tx] = src[(long)(r0+rr)*C + (c0+tx)];
  }
  __syncthreads();
  unsigned short* dh = hi + (long)b*R*C;
  unsigned short* dl = lo + (long)b*R*C;
#pragma unroll
  for (int j=0;j<4;j++){
    int cc = ty + j*8;
    float v = tile[tx][cc];
    long o = (long)(c0+cc)*R + (r0+tx);
    unsigned short h_ = f2bf(v);
    dh[o] = h_;
    dl[o] = f2bf(v - bf2f(h_));
  }
}

// ---------- embedding gather: h fp32 + hi/lo bf16 planes ----------
__global__ void k_gather(const int* __restrict__ ids, const float* __restrict__ embed,
                         float* __restrict__ h, unsigned short* __restrict__ h_hi,
                         unsigned short* __restrict__ h_lo){
  const int t = blockIdx.x, tid = threadIdx.x;
  const int id = ids[t];
  float4 v = ((const float4*)(embed + (long)id*DM))[tid];
  ((float4*)(h + (long)t*DM))[tid] = v;
  ushort4 hh, ll;
  hh.x = f2bf(v.x); ll.x = f2bf(v.x - bf2f(hh.x));
  hh.y = f2bf(v.y); ll.y = f2bf(v.y - bf2f(hh.y));
  hh.z = f2bf(v.z); ll.z = f2bf(v.z - bf2f(hh.z));
  hh.w = f2bf(v.w); ll.w = f2bf(v.w - bf2f(hh.w));
  ((ushort4*)(h_hi + (long)t*DM))[tid] = hh;
  ((ushort4*)(h_lo + (long)t*DM))[tid] = ll;
}

// ---------- router: one wave per token; fp32 logits, softmax, top-2 ----------
__global__ void k_router(const float* __restrict__ h, const float* __restrict__ rw,
                         int* __restrict__ topk_e, float* __restrict__ topk_p,
                         int* __restrict__ tok_slot){
  const int t = blockIdx.x, lane = threadIdx.x;
  float acc[NE];
#pragma unroll
  for (int e=0;e<NE;e++) acc[e]=0.f;
  for (int i=0;i<DM/64;i++){
    int d = i*64 + lane;
    float hv = h[(long)t*DM + d];
    float4 r0 = ((const float4*)(rw + (long)d*NE))[0];
    float4 r1 = ((const float4*)(rw + (long)d*NE))[1];
    acc[0]+=hv*r0.x; acc[1]+=hv*r0.y; acc[2]+=hv*r0.z; acc[3]+=hv*r0.w;
    acc[4]+=hv*r1.x; acc[5]+=hv*r1.y; acc[6]+=hv*r1.z; acc[7]+=hv*r1.w;
  }
#pragma unroll
  for (int e=0;e<NE;e++){
#pragma unroll
    for (int off=32; off>=1; off>>=1) acc[e] += __shfl_xor(acc[e], off, 64);
  }
  if (lane==0){
    int e1=-1; float v1=-1e30f;
    for (int e=0;e<NE;e++) if (acc[e] > v1){ v1=acc[e]; e1=e; }
    int e2=-1; float v2=-1e30f;
    for (int e=0;e<NE;e++) if (e!=e1 && acc[e] > v2){ v2=acc[e]; e2=e; }
    float s=0.f;
    for (int e=0;e<NE;e++) s += expf(acc[e]-v1);
    topk_e[2*t]   = e1;  topk_e[2*t+1] = e2;
    topk_p[2*t]   = 1.0f/s;
    topk_p[2*t+1] = expf(v2-v1)/s;
    tok_slot[2*t] = -1;  tok_slot[2*t+1] = -1;
  }
}

// ---------- capacity: 8 waves, one expert each; sequential ballot scan ----------
__global__ void k_capacity(const int* __restrict__ topk_e, int* __restrict__ slot_token,
                           int* __restrict__ tok_slot){
  const int e = threadIdx.x >> 6, lane = threadIdx.x & 63;
  int running = 0;
  for (int base=0; base<TK; base+=64){
    int t = base + lane;
    int ea = topk_e[2*t], eb = topk_e[2*t+1];
    bool m = (ea==e) || (eb==e);
    unsigned long long bm = __ballot(m);
    int pre = __popcll(bm & (~0ull >> (63-lane)));   // inclusive rank within chunk
    if (m){
      int rank = running + pre;                       // inclusive cumulative rank
      if (rank <= CAP){
        int slot = rank - 1;
        slot_token[e*CAP + slot] = t;
        int j = (ea==e) ? 0 : 1;
        tok_slot[2*t+j] = e*CAP + slot;
      }
    }
    running += __popcll(bm);
  }
  int total = running < CAP ? running : CAP;
  for (int s = total + lane; s < CAP; s += 64) slot_token[e*CAP+s] = -1;
}

// ---------- MFMA GEMM: C[M,N] = A[M,K] * B'[N,K]^T (NT), 128x128x32 tiles ----------
// SPLIT: 3-term hi/lo bf16 (near-fp32).  GATHER: A rows via slot_token list.
// EPI 0: fp32 store.  EPI 1: gelu -> bf16 (hi, + lo if SPLIT).
template<bool SPLIT, bool GATHER, int EPI>
__global__ __launch_bounds__(256) void k_gemm(
    const unsigned short* __restrict__ Ahi, const unsigned short* __restrict__ Alo,
    const unsigned short* __restrict__ Bhi, const unsigned short* __restrict__ Blo,
    const int* __restrict__ rows,
    float* __restrict__ Cf, unsigned short* __restrict__ Chi, unsigned short* __restrict__ Clo,
    int K, int lda, int ldb, int ldc,
    long sA, long sB, long sC)
{
  constexpr int LDSW = 40;   // 32 + 8 pad: 16B-aligned rows, benign 2-way banking
  __shared__ unsigned short As_hi[128*LDSW];
  __shared__ unsigned short Bs_hi[128*LDSW];
  __shared__ unsigned short As_lo[SPLIT ? 128*LDSW : 64];
  __shared__ unsigned short Bs_lo[SPLIT ? 128*LDSW : 64];

  const int bm = blockIdx.x, bn = blockIdx.y, bz = blockIdx.z;
  const int tid = threadIdx.x;
  const int wid = tid>>6, lane = tid&63;
  const int wm = wid>>1, wn = wid&1;
  const int quad = lane>>4, l16 = lane&15;
  const int r = tid>>1, ccol = (tid&1)*16;

  const unsigned short* Abh = Ahi + (long)bz*sA;
  const unsigned short* Abl = SPLIT ? (Alo + (long)bz*sA) : Ahi;
  const unsigned short* Bbh = Bhi + (long)bz*sB;
  const unsigned short* Bbl = SPLIT ? (Blo + (long)bz*sB) : Bhi;

  long arow; bool avalid;
  if constexpr (GATHER){
    int t = rows[bz*CAP + bm*128 + r];
    avalid = (t >= 0); arow = avalid ? t : 0;
  } else { avalid = true; arow = (long)bm*128 + r; }
  const long aoff = arow*(long)lda + ccol;
  const long boff = ((long)bn*128 + r)*(long)ldb + ccol;

  uint4 ra0, ra1, rb0, rb1, ra0l, ra1l, rb0l, rb1l;
  const uint4 zz = make_uint4(0,0,0,0);

  auto stage_load = [&](int k0){
    if (avalid){
      ra0 = *(const uint4*)(Abh + aoff + k0);
      ra1 = *(const uint4*)(Abh + aoff + k0 + 8);
      if constexpr (SPLIT){
        ra0l = *(const uint4*)(Abl + aoff + k0);
        ra1l = *(const uint4*)(Abl + aoff + k0 + 8);
      }
    } else {
      ra0 = zz; ra1 = zz;
      if constexpr (SPLIT){ ra0l = zz; ra1l = zz; }
    }
    rb0 = *(const uint4*)(Bbh + boff + k0);
    rb1 = *(const uint4*)(Bbh + boff + k0 + 8);
    if constexpr (SPLIT){
      rb0l = *(const uint4*)(Bbl + boff + k0);
      rb1l = *(const uint4*)(Bbl + boff + k0 + 8);
    }
  };
  auto stage_store = [&](){
    *(uint4*)&As_hi[r*LDSW + ccol]     = ra0;
    *(uint4*)&As_hi[r*LDSW + ccol + 8] = ra1;
    *(uint4*)&Bs_hi[r*LDSW + ccol]     = rb0;
    *(uint4*)&Bs_hi[r*LDSW + ccol + 8] = rb1;
    if constexpr (SPLIT){
      *(uint4*)&As_lo[r*LDSW + ccol]     = ra0l;
      *(uint4*)&As_lo[r*LDSW + ccol + 8] = ra1l;
      *(uint4*)&Bs_lo[r*LDSW + ccol]     = rb0l;
      *(uint4*)&Bs_lo[r*LDSW + ccol + 8] = rb1l;
    }
  };

  floatx4 acc[4][4] = {};
  const int KT = K >> 5;
  stage_load(0);
  for (int kt=0; kt<KT; ++kt){
    __syncthreads();
    stage_store();
    __syncthreads();
    if (kt+1 < KT) stage_load((kt+1) << 5);

    bf16x8 ah[4], bh[4];
#pragma unroll
    for (int i=0;i<4;i++){
      ah[i] = *(const bf16x8*)&As_hi[(wm*64 + i*16 + l16)*LDSW + quad*8];
      bh[i] = *(const bf16x8*)&Bs_hi[(wn*64 + i*16 + l16)*LDSW + quad*8];
    }
#pragma unroll
    for (int mt=0;mt<4;mt++)
#pragma unroll
      for (int nt=0;nt<4;nt++)
        acc[mt][nt] = __builtin_amdgcn_mfma_f32_16x16x32_bf16(ah[mt], bh[nt], acc[mt][nt], 0,0,0);
    if constexpr (SPLIT){
      bf16x8 al[4], bl[4];
#pragma unroll
      for (int i=0;i<4;i++){
        al[i] = *(const bf16x8*)&As_lo[(wm*64 + i*16 + l16)*LDSW + quad*8];
        bl[i] = *(const bf16x8*)&Bs_lo[(wn*64 + i*16 + l16)*LDSW + quad*8];
      }
#pragma unroll
      for (int mt=0;mt<4;mt++)
#pragma unroll
        for (int nt=0;nt<4;nt++){
          acc[mt][nt] = __builtin_amdgcn_mfma_f32_16x16x32_bf16(ah[mt], bl[nt], acc[mt][nt], 0,0,0);
          acc[mt][nt] = __builtin_amdgcn_mfma_f32_16x16x32_bf16(al[mt], bh[nt], acc[mt][nt], 0,0,0);
        }
    }
  }

  // epilogue: C/D layout col=lane&15, row=quad*4+reg (m89-verified)
  if constexpr (EPI == 0){
    float* Cb = Cf + (long)bz*sC;
#pragma unroll
    for (int mt=0;mt<4;mt++)
#pragma unroll
      for (int nt=0;nt<4;nt++)
#pragma unroll
        for (int i=0;i<4;i++){
          int gr = bm*128 + wm*64 + mt*16 + quad*4 + i;
          int gc = bn*128 + wn*64 + nt*16 + l16;
          Cb[(long)gr*ldc + gc] = acc[mt][nt][i];
        }
  } else {
    unsigned short* Ch = Chi + (long)bz*sC;
    unsigned short* Cl = nullptr;
    if constexpr (SPLIT) Cl = Clo + (long)bz*sC;
#pragma unroll
    for (int mt=0;mt<4;mt++)
#pragma unroll
      for (int nt=0;nt<4;nt++)
#pragma unroll
        for (int i=0;i<4;i++){
          int gr = bm*128 + wm*64 + mt*16 + quad*4 + i;
          int gc = bn*128 + wn*64 + nt*16 + l16;
          float g = gelu_tanh(acc[mt][nt][i]);
          unsigned short hh = f2bf(g);
          long o = (long)gr*ldc + gc;
          Ch[o] = hh;
          if constexpr (SPLIT) Cl[o] = f2bf(g - bf2f(hh));
        }
  }
}

// ================= 256x256 8-phase GEMM (final projection only) =================
// C[M,N] fp32 = A[M,K]bf16 * B[N,K]bf16^T.  BM=BN=256, BK=64, 8 waves (2M x 4N),
// per-wave 128x64 out.  LDS 128 KiB: A/B x 2 dbuf x 2 halves x [128][64] bf16.
// T2: read-side XOR swizzle byte^=(row&7)<<4, applied inverse on the per-lane
// global source (global_load_lds writes linearly).  T3/T4: 8 phases / 2 K-tiles
// per iter, counted vmcnt(4) at phases 4 & 8 only.  T5: setprio around MFMA.
__device__ __forceinline__ void gld_lds16(const void* g, void* l){
  __builtin_amdgcn_global_load_lds((const __attribute__((address_space(1))) void*)g,
                                   (__attribute__((address_space(3))) void*)l, 16, 0, 0);
}

__global__ __launch_bounds__(512, 2) void k_gemm256(
    const unsigned short* __restrict__ A, const unsigned short* __restrict__ B,
    float* __restrict__ C, int K, int ldc, int nbm)
{
  extern __shared__ unsigned short lds[];   // 131072 B
  const int bid = blockIdx.x;
  const int bm = bid % nbm, bn = bid / nbm;  // bm == XCD id for nbm==8: A-panel pinned per-XCD L2
  const int tid = threadIdx.x;
  const int wid = tid >> 6, lane = tid & 63;
  const int wm = wid >> 2, wn = wid & 3;
  const int l16 = lane & 15, quad = lane >> 4;

  // staging geometry: wave wid, call j covers LDS bytes [(j*8+wid)*1024, +1024)
  // row-in-half = (j*8+wid)*8 + (lane>>3); natural colbyte = ((lane&7)^(lane>>3))*16
  const int srow = wid*8 + (lane>>3);
  const int scol = ((lane&7) ^ (lane>>3)) << 3;      // elements

  const unsigned short* Agl = A + ((long)bm*256 + srow)*(long)K + scol;
  const unsigned short* Bgl = B + ((long)bn*256 + srow)*(long)K + scol;
  const long rK64  = (long)64*K;
  const long rK128 = (long)128*K;

  floatx4 acc[8][4] = {};
  bf16x8 a[4][2], b[4][2];

#define STAGE_A(bufi, half, kt) do{ \
    const unsigned short* g_ = Agl + (half)*rK128 + (long)(kt)*64; \
    unsigned short* l_ = lds + ((bufi)*2+(half))*8192 + wid*512; \
    gld_lds16(g_, l_); gld_lds16(g_ + rK64, l_ + 4096); }while(0)
#define STAGE_B(bufi, half, kt) do{ \
    const unsigned short* g_ = Bgl + (half)*rK128 + (long)(kt)*64; \
    unsigned short* l_ = lds + 32768 + ((bufi)*2+(half))*8192 + wid*512; \
    gld_lds16(g_, l_); gld_lds16(g_ + rK64, l_ + 4096); }while(0)

#define LDF(slot, rh, kk) \
    (*(const bf16x8*)((const char*)(slot) + (((((rh)<<7) + (kk)*64 + ((quad)<<4))) ^ (((rh)&7)<<4))))

#define LOAD_A4(bufi, mq) do{ \
    const unsigned short* s_ = lds + ((bufi)*2 + wm)*8192; \
    _Pragma("unroll") for (int m_=0;m_<4;m_++){ \
      int rh_ = ((mq)*4+m_)*16 + l16; \
      a[m_][0] = LDF(s_, rh_, 0); a[m_][1] = LDF(s_, rh_, 1); } }while(0)
#define LOAD_B2(bufi, nh) do{ \
    const unsigned short* s_ = lds + 32768 + ((bufi)*2 + (wn>>1))*8192; \
    _Pragma("unroll") for (int n_=0;n_<2;n_++){ \
      int rh_ = (wn&1)*64 + ((nh)*2+n_)*16 + l16; \
      b[(nh)*2+n_][0] = LDF(s_, rh_, 0); b[(nh)*2+n_][1] = LDF(s_, rh_, 1); } }while(0)

#define PH_SYNC() do{ \
    __builtin_amdgcn_s_barrier(); \
    asm volatile("s_waitcnt lgkmcnt(0)" ::: "memory"); \
    __builtin_amdgcn_sched_barrier(0); }while(0)

#define MFMA_QUAD(mq, nq) do{ \
    __builtin_amdgcn_s_setprio(1); \
    _Pragma("unroll") for (int m_=0;m_<4;m_++) \
    _Pragma("unroll") for (int n_=0;n_<2;n_++) \
    _Pragma("unroll") for (int kk_=0;kk_<2;kk_++) \
      acc[(mq)*4+m_][(nq)*2+n_] = __builtin_amdgcn_mfma_f32_16x16x32_bf16( \
        a[m_][kk_], b[(nq)*2+n_][kk_], acc[(mq)*4+m_][(nq)*2+n_], 0,0,0); \
    __builtin_amdgcn_s_setprio(0); \
    __builtin_amdgcn_s_barrier(); }while(0)

  // prologue: tile0 A+B (buf0), tile1 B (buf1); tile0 fully landed, tile1.B in flight
  STAGE_A(0,0,0); STAGE_A(0,1,0);
  STAGE_B(0,0,0); STAGE_B(0,1,0);
  STAGE_B(1,0,1); STAGE_B(1,1,1);
  asm volatile("s_waitcnt vmcnt(4)" ::: "memory");
  __builtin_amdgcn_s_barrier();

  const int NI = K >> 7;     // 2 K-tiles (BK=64) per iteration
#pragma unroll 1
  for (int i = 0; i < NI-1; ++i){
    const int tb = 2*i+1, t2 = 2*i+2, t3 = 2*i+3;
    // P0
    LOAD_A4(0,0); LOAD_B2(0,0); STAGE_A(1,0,tb);
    PH_SYNC(); MFMA_QUAD(0,0);
    // P1
    LOAD_B2(0,1); STAGE_A(1,1,tb);
    PH_SYNC(); MFMA_QUAD(0,1);
    // P2
    LOAD_A4(0,1); STAGE_B(0,0,t2);
    PH_SYNC(); MFMA_QUAD(1,0);
    // P3
    STAGE_B(0,1,t2);
    asm volatile("s_waitcnt vmcnt(4)" ::: "memory");
    PH_SYNC(); MFMA_QUAD(1,1);
    // P4
    LOAD_A4(1,0); LOAD_B2(1,0); STAGE_A(0,0,t2);
    PH_SYNC(); MFMA_QUAD(0,0);
    // P5
    LOAD_B2(1,1); STAGE_A(0,1,t2);
    PH_SYNC(); MFMA_QUAD(0,1);
    // P6
    LOAD_A4(1,1); STAGE_B(1,0,t3);
    PH_SYNC(); MFMA_QUAD(1,0);
    // P7
    STAGE_B(1,1,t3);
    asm volatile("s_waitcnt vmcnt(4)" ::: "memory");
    PH_SYNC(); MFMA_QUAD(1,1);
  }
  { // peeled last iteration: tiles 2*NI-2 (buf0), 2*NI-1 (buf1); no forward stages
    const int tb = 2*NI-1;
    LOAD_A4(0,0); LOAD_B2(0,0); STAGE_A(1,0,tb);
    PH_SYNC(); MFMA_QUAD(0,0);
    LOAD_B2(0,1); STAGE_A(1,1,tb);
    PH_SYNC(); MFMA_QUAD(0,1);
    LOAD_A4(0,1);
    PH_SYNC(); MFMA_QUAD(1,0);
    asm volatile("s_waitcnt vmcnt(0)" ::: "memory");
    PH_SYNC(); MFMA_QUAD(1,1);
    LOAD_A4(1,0); LOAD_B2(1,0);
    PH_SYNC(); MFMA_QUAD(0,0);
    LOAD_B2(1,1);
    PH_SYNC(); MFMA_QUAD(0,1);
    LOAD_A4(1,1);
    PH_SYNC(); MFMA_QUAD(1,0);
    PH_SYNC(); MFMA_QUAD(1,1);
  }
#undef STAGE_A
#undef STAGE_B
#undef LDF
#undef LOAD_A4
#undef LOAD_B2
#undef PH_SYNC
#undef MFMA_QUAD

  // epilogue: C/D layout col=lane&15, row=quad*4+reg
  float* Cp = C + ((long)bm*256 + wm*128 + quad*4)*(long)ldc + (long)bn*256 + wn*64 + l16;
#pragma unroll
  for (int m_=0;m_<8;m_++)
#pragma unroll
    for (int n_=0;n_<4;n_++)
#pragma unroll
      for (int i_=0;i_<4;i_++)
        Cp[(long)(m_*16 + i_)*ldc + n_*16] = acc[m_][n_][i_];
}

// ---------- combine: h = (1-rho)*h + sum_j w_j * out_e[slot_j] ----------
__global__ void k_combine(float* __restrict__ h, unsigned short* __restrict__ h_hi,
                          const float* __restrict__ out_e,
                          const int* __restrict__ tok_slot, const float* __restrict__ topk_p){
  const int t = blockIdx.x, tid = threadIdx.x;
  const int s0 = tok_slot[2*t], s1 = tok_slot[2*t+1];
  const float w0 = (s0>=0) ? topk_p[2*t]   : 0.f;
  const float w1 = (s1>=0) ? topk_p[2*t+1] : 0.f;
  const float sc = 1.f - w0 - w1;
#pragma unroll
  for (int i=0;i<4;i++){
    int d = i*256 + tid;
    float v = sc * h[(long)t*DM + d];
    if (s0>=0) v += w0 * out_e[(long)s0*DM + d];
    if (s1>=0) v += w1 * out_e[(long)s1*DM + d];
    h[(long)t*DM + d] = v;
    h_hi[(long)t*DM + d] = f2bf(v);
  }
}

// ---------- rmsnorm -> bf16 ----------
__global__ void k_rmsnorm(const float* __restrict__ h, const float* __restrict__ lnw,
                          unsigned short* __restrict__ h_hi){
  const int t = blockIdx.x, tid = threadIdx.x;
  const int wid = tid>>6, lane = tid&63;
  float vals[4];
  float ss = 0.f;
#pragma unroll
  for (int i=0;i<4;i++){ vals[i] = h[(long)t*DM + i*256 + tid]; ss += vals[i]*vals[i]; }
#pragma unroll
  for (int off=32; off>=1; off>>=1) ss += __shfl_xor(ss, off, 64);
  __shared__ float red[4];
  __shared__ float scale_s;
  if (lane==0) red[wid] = ss;
  __syncthreads();
  if (tid==0) scale_s = 1.0f / sqrtf((red[0]+red[1]+red[2]+red[3])/(float)DM + 1e-6f);
  __syncthreads();
  float scale = scale_s;
#pragma unroll
  for (int i=0;i<4;i++){
    int d = i*256 + tid;
    h_hi[(long)t*DM + d] = f2bf(vals[i]*scale*lnw[d]);
  }
}

extern "C" void kernel_launch(void* const* d_in, const int* in_sizes, int n_in,
                              void* d_out, int out_size, void* d_ws, size_t ws_size,
                              hipStream_t stream){
  const int*   ids   = (const int*)d_in[0];
  const float* embed = (const float*)d_in[1];
  const float* rw    = (const float*)d_in[2];
  const float* w1    = (const float*)d_in[3];
  const float* w2    = (const float*)d_in[4];
  const float* lnw   = (const float*)d_in[5];

  static bool attr_done = false;
  if (!attr_done){
    hipFuncSetAttribute(reinterpret_cast<const void*>(k_gemm256),
                        hipFuncAttributeMaxDynamicSharedMemorySize, 131072);
    attr_done = true;
  }

  // ws carve (~82.4 MB)
  char* ws = (char*)d_ws;
  auto alloc = [&](size_t b)->char*{ char* p = ws; ws += (b + 255) & ~(size_t)255; return p; };
  unsigned short* embed_bf = (unsigned short*)alloc((size_t)NV*DM*2);
  float*          h        = (float*)alloc((size_t)TK*DM*4);
  unsigned short* h_hi     = (unsigned short*)alloc((size_t)TK*DM*2);
  unsigned short* h_lo     = (unsigned short*)alloc((size_t)TK*DM*2);
  int*   topk_e   = (int*)alloc(TK*2*4);
  float* topk_p   = (float*)alloc(TK*2*4);
  int*   tok_slot = (int*)alloc(TK*2*4);
  int*   slot_tok = (int*)alloc(NE*CAP*4);

  // d_out doubles as scratch (~197 MB < 262 MB); final GEMM overwrites all of it
  char* od = (char*)d_out;
  auto alloc2 = [&](size_t b)->char*{ char* p = od; od += (b + 255) & ~(size_t)255; return p; };
  unsigned short* w1t_hi = (unsigned short*)alloc2((size_t)NE*DM*NF*2);
  unsigned short* w1t_lo = (unsigned short*)alloc2((size_t)NE*DM*NF*2);
  unsigned short* w2t_hi = (unsigned short*)alloc2((size_t)NE*DM*NF*2);
  unsigned short* w2t_lo = (unsigned short*)alloc2((size_t)NE*DM*NF*2);
  unsigned short* act_hi = (unsigned short*)alloc2((size_t)NE*CAP*NF*2);
  unsigned short* act_lo = (unsigned short*)alloc2((size_t)NE*CAP*NF*2);
  float*          out_e  = (float*)alloc2((size_t)NE*CAP*DM*4);

  dim3 tb32(32,8,1);
  // weights -> NT-layout bf16 hi/lo planes
  k_transpose_split<<<dim3(NF/32, DM/32, NE), tb32, 0, stream>>>(w1, w1t_hi, w1t_lo, DM, NF);
  k_transpose_split<<<dim3(DM/32, NF/32, NE), tb32, 0, stream>>>(w2, w2t_hi, w2t_lo, NF, DM);
  k_convert_bf16<<<(int)(((long)NV*DM/4 + 255)/256), 256, 0, stream>>>(embed, embed_bf, (long)NV*DM/4);
  k_gather<<<TK, 256, 0, stream>>>(ids, embed, h, h_hi, h_lo);

  for (int hop=0; hop<2; ++hop){
    k_router<<<TK, 64, 0, stream>>>(h, rw + (long)hop*DM*NE, topk_e, topk_p, tok_slot);
    k_capacity<<<1, 512, 0, stream>>>(topk_e, slot_tok, tok_slot);
    if (hop == 0){
      // split-precision hop 0: protects hop-1 routing decisions
      k_gemm<true,true,1><<<dim3(CAP/128, NF/128, NE), 256, 0, stream>>>(
        h_hi, h_lo, w1t_hi, w1t_lo, slot_tok, nullptr, act_hi, act_lo,
        DM, DM, DM, NF, 0L, (long)NF*DM, (long)CAP*NF);
      k_gemm<true,false,0><<<dim3(CAP/128, DM/128, NE), 256, 0, stream>>>(
        act_hi, act_lo, w2t_hi, w2t_lo, nullptr, out_e, nullptr, nullptr,
        NF, NF, NF, DM, (long)CAP*NF, (long)DM*NF, (long)CAP*DM);
    } else {
      k_gemm<false,true,1><<<dim3(CAP/128, NF/128, NE), 256, 0, stream>>>(
        h_hi, nullptr, w1t_hi, nullptr, slot_tok, nullptr, act_hi, nullptr,
        DM, DM, DM, NF, 0L, (long)NF*DM, (long)CAP*NF);
      k_gemm<false,false,0><<<dim3(CAP/128, DM/128, NE), 256, 0, stream>>>(
        act_hi, nullptr, w2t_hi, nullptr, nullptr, out_e, nullptr, nullptr,
        NF, NF, NF, DM, (long)CAP*NF, (long)DM*NF, (long)CAP*DM);
    }
    k_combine<<<TK, 256, 0, stream>>>(h, h_hi, out_e, tok_slot, topk_p);
  }

  k_rmsnorm<<<TK, 256, 0, stream>>>(h, lnw, h_hi);
  // final tied projection: [2048,1024] x [32000,1024]^T -> d_out fp32
  // 256^2 8-phase kernel: grid 8 x 125, bm = bid%8 pins one A-panel per XCD
  k_gemm256<<<dim3(8*(NV/256)), 512, 131072, stream>>>(
    h_hi, embed_bf, (float*)d_out, DM, NV, 8);
}

// Round 2
// 1049.279 us; speedup vs baseline: 1.0907x; 1.0907x over previous
//
#include <hip/hip_runtime.h>
#include <cstdint>

#define TK 2048     // tokens
#define DM 1024     // d_model
#define NE 8        // experts
#define NF 2048     // expert hidden
#define NV 32000    // vocab
#define CAP 640     // int(1.25 * 2 * 2048 / 8)

typedef short bf16x8 __attribute__((ext_vector_type(8)));
typedef float floatx4 __attribute__((ext_vector_type(4)));

__device__ __forceinline__ unsigned short f2bf(float x){
  unsigned u = __float_as_uint(x);
  u += 0x7FFFu + ((u >> 16) & 1u);
  return (unsigned short)(u >> 16);
}
__device__ __forceinline__ float bf2f(unsigned short h){
  return __uint_as_float(((unsigned)h) << 16);
}
__device__ __forceinline__ float gelu_tanh(float x){
  float x3 = x*x*x;
  return 0.5f*x*(1.0f + tanhf(0.7978845608028654f*(x + 0.044715f*x3)));
}
// async global->LDS DMA, 16B per lane; LDS base must be wave-uniform, global addr is per-lane
__device__ __forceinline__ void gld_lds16(const unsigned short* g, unsigned short* l){
  __builtin_amdgcn_global_load_lds((const __attribute__((address_space(1))) void*)g,
                                   (__attribute__((address_space(3))) void*)l, 16, 0, 0);
}

// ---------- fp32 -> bf16 convert (vectorized) ----------
__global__ void k_convert_bf16(const float* __restrict__ in, unsigned short* __restrict__ out, long n4){
  long i = (long)blockIdx.x*blockDim.x + threadIdx.x;
  if (i >= n4) return;
  float4 v = ((const float4*)in)[i];
  ushort4 o;
  o.x = f2bf(v.x); o.y = f2bf(v.y); o.z = f2bf(v.z); o.w = f2bf(v.w);
  ((ushort4*)out)[i] = o;
}

// ---------- batched transpose fp32 [B,R,C] -> bf16 hi/lo [B,C,R] ----------
__global__ void k_transpose_split(const float* __restrict__ in, unsigned short* __restrict__ hi,
                                  unsigned short* __restrict__ lo, int R, int C){
  __shared__ float tile[32][33];
  const int b = blockIdx.z;
  const float* src = in + (long)b*R*C;
  const int c0 = blockIdx.x*32, r0 = blockIdx.y*32;
  const int tx = threadIdx.x, ty = threadIdx.y;
#pragma unroll
  for (int j=0;j<4;j++){
    int rr = ty + j*8;
    tile[rr][tx] = src[(long)(r0+rr)*C + (c0+tx)];
  }
  __syncthreads();
  unsigned short* dh = hi + (long)b*R*C;
  unsigned short* dl = lo + (long)b*R*C;
#pragma unroll
  for (int j=0;j<4;j++){
    int cc = ty + j*8;
    float v = tile[tx][cc];
    long o = (long)(c0+cc)*R + (r0+tx);
    unsigned short h_ = f2bf(v);
    dh[o] = h_;
    dl[o] = f2bf(v - bf2f(h_));
  }
}

// ---------- embedding gather: h fp32 + hi/lo bf16 planes ----------
__global__ void k_gather(const int* __restrict__ ids, const float* __restrict__ embed,
                         float* __restrict__ h, unsigned short* __restrict__ h_hi,
                         unsigned short* __restrict__ h_lo){
  const int t = blockIdx.x, tid = threadIdx.x;
  const int id = ids[t];
  float4 v = ((const float4*)(embed + (long)id*DM))[tid];
  ((float4*)(h + (long)t*DM))[tid] = v;
  ushort4 hh, ll;
  hh.x = f2bf(v.x); ll.x = f2bf(v.x - bf2f(hh.x));
  hh.y = f2bf(v.y); ll.y = f2bf(v.y - bf2f(hh.y));
  hh.z = f2bf(v.z); ll.z = f2bf(v.z - bf2f(hh.z));
  hh.w = f2bf(v.w); ll.w = f2bf(v.w - bf2f(hh.w));
  ((ushort4*)(h_hi + (long)t*DM))[tid] = hh;
  ((ushort4*)(h_lo + (long)t*DM))[tid] = ll;
}

// ---------- router: one wave per token; fp32 logits, softmax, top-2 ----------
__global__ void k_router(const float* __restrict__ h, const float* __restrict__ rw,
                         int* __restrict__ topk_e, float* __restrict__ topk_p,
                         int* __restrict__ tok_slot){
  const int t = blockIdx.x, lane = threadIdx.x;
  float acc[NE];
#pragma unroll
  for (int e=0;e<NE;e++) acc[e]=0.f;
  for (int i=0;i<DM/64;i++){
    int d = i*64 + lane;
    float hv = h[(long)t*DM + d];
    float4 r0 = ((const float4*)(rw + (long)d*NE))[0];
    float4 r1 = ((const float4*)(rw + (long)d*NE))[1];
    acc[0]+=hv*r0.x; acc[1]+=hv*r0.y; acc[2]+=hv*r0.z; acc[3]+=hv*r0.w;
    acc[4]+=hv*r1.x; acc[5]+=hv*r1.y; acc[6]+=hv*r1.z; acc[7]+=hv*r1.w;
  }
#pragma unroll
  for (int e=0;e<NE;e++){
#pragma unroll
    for (int off=32; off>=1; off>>=1) acc[e] += __shfl_xor(acc[e], off, 64);
  }
  if (lane==0){
    int e1=-1; float v1=-1e30f;
    for (int e=0;e<NE;e++) if (acc[e] > v1){ v1=acc[e]; e1=e; }
    int e2=-1; float v2=-1e30f;
    for (int e=0;e<NE;e++) if (e!=e1 && acc[e] > v2){ v2=acc[e]; e2=e; }
    float s=0.f;
    for (int e=0;e<NE;e++) s += expf(acc[e]-v1);
    topk_e[2*t]   = e1;  topk_e[2*t+1] = e2;
    topk_p[2*t]   = 1.0f/s;
    topk_p[2*t+1] = expf(v2-v1)/s;
    tok_slot[2*t] = -1;  tok_slot[2*t+1] = -1;
  }
}

// ---------- capacity: 8 waves, one expert each; sequential ballot scan ----------
__global__ void k_capacity(const int* __restrict__ topk_e, int* __restrict__ slot_token,
                           int* __restrict__ tok_slot){
  const int e = threadIdx.x >> 6, lane = threadIdx.x & 63;
  int running = 0;
  for (int base=0; base<TK; base+=64){
    int t = base + lane;
    int ea = topk_e[2*t], eb = topk_e[2*t+1];
    bool m = (ea==e) || (eb==e);
    unsigned long long bm = __ballot(m);
    int pre = __popcll(bm & (~0ull >> (63-lane)));   // inclusive rank within chunk
    if (m){
      int rank = running + pre;                       // inclusive cumulative rank
      if (rank <= CAP){
        int slot = rank - 1;
        slot_token[e*CAP + slot] = t;
        int j = (ea==e) ? 0 : 1;
        tok_slot[2*t+j] = e*CAP + slot;
      }
    }
    running += __popcll(bm);
  }
  int total = running < CAP ? running : CAP;
  for (int s = total + lane; s < CAP; s += 64) slot_token[e*CAP+s] = -1;
}

// ---------- MFMA GEMM: C[M,N] = A[M,K] * B'[N,K]^T (NT), 128x128x32 tiles ----------
// Staging: global_load_lds width-16 DMA (m97/m193: +67% over reg-staging at this tile).
// LDS layout: linear row-major [128][32] (DMA requires linear dest; lane i of wave w,
// call j lands at chunk (w*2+j)*1024B + lane*16B = row (w*2+j)*16 + lane/4, col (lane&3)*8).
// SPLIT: 3-term hi/lo bf16 (near-fp32).  GATHER: A rows via slot_token list (DMA global
// addr is per-lane, so gather works; invalid rows read row 0 — garbage lands only in
// slots that are never combined).
// EPI 0: fp32 store.  EPI 1: gelu -> bf16 (hi, + lo if SPLIT).
template<bool SPLIT, bool GATHER, int EPI>
__global__ __launch_bounds__(256) void k_gemm(
    const unsigned short* __restrict__ Ahi, const unsigned short* __restrict__ Alo,
    const unsigned short* __restrict__ Bhi, const unsigned short* __restrict__ Blo,
    const int* __restrict__ rows,
    float* __restrict__ Cf, unsigned short* __restrict__ Chi, unsigned short* __restrict__ Clo,
    int K, int lda, int ldb, int ldc,
    long sA, long sB, long sC)
{
  constexpr int LDSW = 32;   // linear: global_load_lds writes base + lane*16B contiguously
  __shared__ unsigned short As_hi[128*LDSW];
  __shared__ unsigned short Bs_hi[128*LDSW];
  __shared__ unsigned short As_lo[SPLIT ? 128*LDSW : 64];
  __shared__ unsigned short Bs_lo[SPLIT ? 128*LDSW : 64];

  const int bm = blockIdx.x, bn = blockIdx.y, bz = blockIdx.z;
  const int tid = threadIdx.x;
  const int wid = tid>>6, lane = tid&63;
  const int wm = wid>>1, wn = wid&1;
  const int quad = lane>>4, l16 = lane&15;

  const unsigned short* Abh = Ahi + (long)bz*sA;
  const unsigned short* Abl = SPLIT ? (Alo + (long)bz*sA) : Ahi;
  const unsigned short* Bbh = Bhi + (long)bz*sB;
  const unsigned short* Bbl = SPLIT ? (Blo + (long)bz*sB) : Bhi;

  // DMA staging geometry: wave wid covers rows [wid*32, wid*32+32) in two 16-row calls
  const int srow0 = wid*32 + (lane>>2);     // call j=0 row
  const int srow1 = srow0 + 16;             // call j=1 row
  const int scol  = (lane&3)*8;             // 8 bf16 = 16B per lane

  long arow0, arow1;
  if constexpr (GATHER){
    int t0 = rows[bz*CAP + bm*128 + srow0];
    int t1 = rows[bz*CAP + bm*128 + srow1];
    arow0 = (t0 >= 0) ? t0 : 0;             // invalid -> row 0 (finite garbage, never consumed)
    arow1 = (t1 >= 0) ? t1 : 0;
  } else {
    arow0 = (long)bm*128 + srow0;
    arow1 = (long)bm*128 + srow1;
  }
  const unsigned short* Ah0 = Abh + arow0*(long)lda + scol;
  const unsigned short* Ah1 = Abh + arow1*(long)lda + scol;
  const unsigned short* Al0 = Abl + arow0*(long)lda + scol;
  const unsigned short* Al1 = Abl + arow1*(long)lda + scol;
  const unsigned short* Bh0 = Bbh + ((long)bn*128 + srow0)*(long)ldb + scol;
  const unsigned short* Bh1 = Bbh + ((long)bn*128 + srow1)*(long)ldb + scol;
  const unsigned short* Bl0 = Bbl + ((long)bn*128 + srow0)*(long)ldb + scol;
  const unsigned short* Bl1 = Bbl + ((long)bn*128 + srow1)*(long)ldb + scol;

  unsigned short* AsD = As_hi + wid*1024;   // wave-uniform LDS chunk base (2 KiB/wave)
  unsigned short* BsD = Bs_hi + wid*1024;
  unsigned short* AsDl = As_lo + wid*1024;
  unsigned short* BsDl = Bs_lo + wid*1024;

  floatx4 acc[4][4] = {};
  const int KT = K >> 5;
  for (int kt=0; kt<KT; ++kt){
    const int k0 = kt << 5;
    __syncthreads();                        // prior reads done before overwrite
    gld_lds16(Ah0 + k0, AsD);
    gld_lds16(Ah1 + k0, AsD + 512);
    gld_lds16(Bh0 + k0, BsD);
    gld_lds16(Bh1 + k0, BsD + 512);
    if constexpr (SPLIT){
      gld_lds16(Al0 + k0, AsDl);
      gld_lds16(Al1 + k0, AsDl + 512);
      gld_lds16(Bl0 + k0, BsDl);
      gld_lds16(Bl1 + k0, BsDl + 512);
    }
    __syncthreads();                        // compiler drains vmcnt(0) before barrier

    bf16x8 ah[4], bh[4];
#pragma unroll
    for (int i=0;i<4;i++){
      ah[i] = *(const bf16x8*)&As_hi[(wm*64 + i*16 + l16)*LDSW + quad*8];
      bh[i] = *(const bf16x8*)&Bs_hi[(wn*64 + i*16 + l16)*LDSW + quad*8];
    }
#pragma unroll
    for (int mt=0;mt<4;mt++)
#pragma unroll
      for (int nt=0;nt<4;nt++)
        acc[mt][nt] = __builtin_amdgcn_mfma_f32_16x16x32_bf16(ah[mt], bh[nt], acc[mt][nt], 0,0,0);
    if constexpr (SPLIT){
      bf16x8 al[4], bl[4];
#pragma unroll
      for (int i=0;i<4;i++){
        al[i] = *(const bf16x8*)&As_lo[(wm*64 + i*16 + l16)*LDSW + quad*8];
        bl[i] = *(const bf16x8*)&Bs_lo[(wn*64 + i*16 + l16)*LDSW + quad*8];
      }
#pragma unroll
      for (int mt=0;mt<4;mt++)
#pragma unroll
        for (int nt=0;nt<4;nt++){
          acc[mt][nt] = __builtin_amdgcn_mfma_f32_16x16x32_bf16(ah[mt], bl[nt], acc[mt][nt], 0,0,0);
          acc[mt][nt] = __builtin_amdgcn_mfma_f32_16x16x32_bf16(al[mt], bh[nt], acc[mt][nt], 0,0,0);
        }
    }
  }

  // epilogue: C/D layout col=lane&15, row=quad*4+reg (m89-verified)
  if constexpr (EPI == 0){
    float* Cb = Cf + (long)bz*sC;
#pragma unroll
    for (int mt=0;mt<4;mt++)
#pragma unroll
      for (int nt=0;nt<4;nt++)
#pragma unroll
        for (int i=0;i<4;i++){
          int gr = bm*128 + wm*64 + mt*16 + quad*4 + i;
          int gc = bn*128 + wn*64 + nt*16 + l16;
          Cb[(long)gr*ldc + gc] = acc[mt][nt][i];
        }
  } else {
    unsigned short* Ch = Chi + (long)bz*sC;
    unsigned short* Cl = nullptr;
    if constexpr (SPLIT) Cl = Clo + (long)bz*sC;
#pragma unroll
    for (int mt=0;mt<4;mt++)
#pragma unroll
      for (int nt=0;nt<4;nt++)
#pragma unroll
        for (int i=0;i<4;i++){
          int gr = bm*128 + wm*64 + mt*16 + quad*4 + i;
          int gc = bn*128 + wn*64 + nt*16 + l16;
          float g = gelu_tanh(acc[mt][nt][i]);
          unsigned short hh = f2bf(g);
          long o = (long)gr*ldc + gc;
          Ch[o] = hh;
          if constexpr (SPLIT) Cl[o] = f2bf(g - bf2f(hh));
        }
  }
}

// ---------- combine: h = (1-rho)*h + sum_j w_j * out_e[slot_j] ----------
__global__ void k_combine(float* __restrict__ h, unsigned short* __restrict__ h_hi,
                          const float* __restrict__ out_e,
                          const int* __restrict__ tok_slot, const float* __restrict__ topk_p){
  const int t = blockIdx.x, tid = threadIdx.x;
  const int s0 = tok_slot[2*t], s1 = tok_slot[2*t+1];
  const float w0 = (s0>=0) ? topk_p[2*t]   : 0.f;
  const float w1 = (s1>=0) ? topk_p[2*t+1] : 0.f;
  const float sc = 1.f - w0 - w1;
#pragma unroll
  for (int i=0;i<4;i++){
    int d = i*256 + tid;
    float v = sc * h[(long)t*DM + d];
    if (s0>=0) v += w0 * out_e[(long)s0*DM + d];
    if (s1>=0) v += w1 * out_e[(long)s1*DM + d];
    h[(long)t*DM + d] = v;
    h_hi[(long)t*DM + d] = f2bf(v);
  }
}

// ---------- rmsnorm -> bf16 ----------
__global__ void k_rmsnorm(const float* __restrict__ h, const float* __restrict__ lnw,
                          unsigned short* __restrict__ h_hi){
  const int t = blockIdx.x, tid = threadIdx.x;
  const int wid = tid>>6, lane = tid&63;
  float vals[4];
  float ss = 0.f;
#pragma unroll
  for (int i=0;i<4;i++){ vals[i] = h[(long)t*DM + i*256 + tid]; ss += vals[i]*vals[i]; }
#pragma unroll
  for (int off=32; off>=1; off>>=1) ss += __shfl_xor(ss, off, 64);
  __shared__ float red[4];
  __shared__ float scale_s;
  if (lane==0) red[wid] = ss;
  __syncthreads();
  if (tid==0) scale_s = 1.0f / sqrtf((red[0]+red[1]+red[2]+red[3])/(float)DM + 1e-6f);
  __syncthreads();
  float scale = scale_s;
#pragma unroll
  for (int i=0;i<4;i++){
    int d = i*256 + tid;
    h_hi[(long)t*DM + d] = f2bf(vals[i]*scale*lnw[d]);
  }
}

extern "C" void kernel_launch(void* const* d_in, const int* in_sizes, int n_in,
                              void* d_out, int out_size, void* d_ws, size_t ws_size,
                              hipStream_t stream){
  const int*   ids   = (const int*)d_in[0];
  const float* embed = (const float*)d_in[1];
  const float* rw    = (const float*)d_in[2];
  const float* w1    = (const float*)d_in[3];
  const float* w2    = (const float*)d_in[4];
  const float* lnw   = (const float*)d_in[5];

  // ws carve (~82.4 MB)
  char* ws = (char*)d_ws;
  auto alloc = [&](size_t b)->char*{ char* p = ws; ws += (b + 255) & ~(size_t)255; return p; };
  unsigned short* embed_bf = (unsigned short*)alloc((size_t)NV*DM*2);
  float*          h        = (float*)alloc((size_t)TK*DM*4);
  unsigned short* h_hi     = (unsigned short*)alloc((size_t)TK*DM*2);
  unsigned short* h_lo     = (unsigned short*)alloc((size_t)TK*DM*2);
  int*   topk_e   = (int*)alloc(TK*2*4);
  float* topk_p   = (float*)alloc(TK*2*4);
  int*   tok_slot = (int*)alloc(TK*2*4);
  int*   slot_tok = (int*)alloc(NE*CAP*4);

  // d_out doubles as scratch (~197 MB < 262 MB); final GEMM overwrites all of it
  char* od = (char*)d_out;
  auto alloc2 = [&](size_t b)->char*{ char* p = od; od += (b + 255) & ~(size_t)255; return p; };
  unsigned short* w1t_hi = (unsigned short*)alloc2((size_t)NE*DM*NF*2);
  unsigned short* w1t_lo = (unsigned short*)alloc2((size_t)NE*DM*NF*2);
  unsigned short* w2t_hi = (unsigned short*)alloc2((size_t)NE*DM*NF*2);
  unsigned short* w2t_lo = (unsigned short*)alloc2((size_t)NE*DM*NF*2);
  unsigned short* act_hi = (unsigned short*)alloc2((size_t)NE*CAP*NF*2);
  unsigned short* act_lo = (unsigned short*)alloc2((size_t)NE*CAP*NF*2);
  float*          out_e  = (float*)alloc2((size_t)NE*CAP*DM*4);

  dim3 tb32(32,8,1);
  // weights -> NT-layout bf16 hi/lo planes
  k_transpose_split<<<dim3(NF/32, DM/32, NE), tb32, 0, stream>>>(w1, w1t_hi, w1t_lo, DM, NF);
  k_transpose_split<<<dim3(DM/32, NF/32, NE), tb32, 0, stream>>>(w2, w2t_hi, w2t_lo, NF, DM);
  k_convert_bf16<<<(int)(((long)NV*DM/4 + 255)/256), 256, 0, stream>>>(embed, embed_bf, (long)NV*DM/4);
  k_gather<<<TK, 256, 0, stream>>>(ids, embed, h, h_hi, h_lo);

  for (int hop=0; hop<2; ++hop){
    k_router<<<TK, 64, 0, stream>>>(h, rw + (long)hop*DM*NE, topk_e, topk_p, tok_slot);
    k_capacity<<<1, 512, 0, stream>>>(topk_e, slot_tok, tok_slot);
    if (hop == 0){
      // split-precision hop 0: protects hop-1 routing decisions
      k_gemm<true,true,1><<<dim3(CAP/128, NF/128, NE), 256, 0, stream>>>(
        h_hi, h_lo, w1t_hi, w1t_lo, slot_tok, nullptr, act_hi, act_lo,
        DM, DM, DM, NF, 0L, (long)NF*DM, (long)CAP*NF);
      k_gemm<true,false,0><<<dim3(CAP/128, DM/128, NE), 256, 0, stream>>>(
        act_hi, act_lo, w2t_hi, w2t_lo, nullptr, out_e, nullptr, nullptr,
        NF, NF, NF, DM, (long)CAP*NF, (long)DM*NF, (long)CAP*DM);
    } else {
      k_gemm<false,true,1><<<dim3(CAP/128, NF/128, NE), 256, 0, stream>>>(
        h_hi, nullptr, w1t_hi, nullptr, slot_tok, nullptr, act_hi, nullptr,
        DM, DM, DM, NF, 0L, (long)NF*DM, (long)CAP*NF);
      k_gemm<false,false,0><<<dim3(CAP/128, DM/128, NE), 256, 0, stream>>>(
        act_hi, nullptr, w2t_hi, nullptr, nullptr, out_e, nullptr, nullptr,
        NF, NF, NF, DM, (long)CAP*NF, (long)DM*NF, (long)CAP*DM);
    }
    k_combine<<<TK, 256, 0, stream>>>(h, h_hi, out_e, tok_slot, topk_p);
  }

  k_rmsnorm<<<TK, 256, 0, stream>>>(h, lnw, h_hi);
  // final tied projection: [2048,1024] x [32000,1024]^T -> d_out fp32
  k_gemm<false,false,0><<<dim3(TK/128, NV/128, 1), 256, 0, stream>>>(
    h_hi, nullptr, embed_bf, nullptr, nullptr, (float*)d_out, nullptr, nullptr,
    DM, DM, DM, NV, 0L, 0L, 0L);
}